// Round 4
// baseline (754.787 us; speedup 1.0000x reference)
//
#include <hip/hip_runtime.h>
#include <hip/hip_bf16.h>
#include <stdint.h>

// SSL hashed-sparse linear: out[M,N] = x[M,K] @ w_full[N,K]^T + bias
// w_full[n,k] = weight[n, h(n/32, k/32)*32 + k%32],
// h = ((kb*r0 + nb*r1 + r2) ^ r3) % num_red_kb   (uint32)
//
// fp32 in/out; compute in bf16 MFMA (threshold 0.165; absmax 0.03).
// ROUND-3..6 history: 2-barrier LDS-staged 128x128 tile, split-K x4:
//   250us (drain barriers) == 247us (counted vmcnt) -> barrier drain NOT the
//   stall. B-direct + 1-deep prefetch: 411us (depth cut hurt). All pipes
//   <15% busy in every variant: the lockstep-barrier structure itself is
//   latency-bound at 2 blocks/CU.
// ROUND-7 (this): BARRIER-FREE, ZERO-LDS, wave-independent rewrite.
//   - W (2MB) is L2-resident -> B frags load straight to regs (verified
//     mapping from round-3 which passed).
//   - A frags load straight to regs too (16 rows x 16B per instr = 16 full
//     cache lines); the wn-wave pair reads A twice -> extra ~256MB from
//     L1/L2 per dispatch = ~7us of L2 BW. Cheap.
//   - No LDS, no barriers, no bank conflicts, no ds ops. Each of 8 waves/CU
//     is an independent load->cvt->MFMA stream; reg double-buffer A (2-deep,
//     ~2 steps ~= HBM latency), 1-deep B (L2 ~250cy). Compiler emits exact
//     counted vmcnt waits -- nothing forces a drain anymore.
//   - __launch_bounds__(256,2): unified cap 256 (acc 64 + in-flight 96 +
//     frags 32 + addr ~=230 fits; NOT a round-1-style clamp).
// Predicted: dur 247->90-150us, conflicts ->0, MfmaUtil ->18-30%,
// VALUBusy ->25-40%. VALUBusy>55% => cvt-bound (go packed/fp8 next);
// all-low => deepen A to 3.

typedef __bf16 bf16x8_t __attribute__((ext_vector_type(8)));
typedef float f32x4 __attribute__((ext_vector_type(4)));

#define BM 128
#define BN 128
#define BK 32
#define KSPLIT 4

__global__ void init_out(float* __restrict__ Out, const float* __restrict__ Bias,
                         int N, int total4) {
  int i = blockIdx.x * blockDim.x + threadIdx.x;
  if (i < total4) {
    int idx = i << 2;
    int n = idx % N;                       // multiple of 4 since N%4==0
    *(f32x4*)(Out + idx) = *(const f32x4*)(Bias + n);
  }
}

__global__ __launch_bounds__(256, 2) void ssl_gemm(
    const float* __restrict__ X,       // [M,K]
    const float* __restrict__ W,       // [N,redK]
    const int* __restrict__ RN,        // [4]
    float* __restrict__ Out,           // [M,N], pre-seeded with bias
    int M, int N, int K, int redK, uint32_t numRedKb, int mTiles, int nTiles) {
  const uint32_t r0 = (uint32_t)RN[0], r1 = (uint32_t)RN[1];
  const uint32_t r2 = (uint32_t)RN[2], r3 = (uint32_t)RN[3];
  const uint32_t redMask = numRedKb - 1u;
  const bool pow2 = (numRedKb & (numRedKb - 1u)) == 0u;

  const int id = blockIdx.x;
  // id = m + mTiles*(n + nTiles*s); mTiles=64 (mult of 8) -> all blocks of an
  // m-tile share id%8 -> same XCD -> L2 reuse of the X stream.
  const int mTile = id % mTiles;
  const int rest = id / mTiles;
  const int nTile = rest % nTiles;
  const int kChunk = rest / nTiles;      // 0..KSPLIT-1

  const int tid = threadIdx.x;
  const int wave = tid >> 6;
  const int lane = tid & 63;
  const int wm = wave >> 1, wn = wave & 1;  // 2x2 wave grid, each 64x64

  const int r16 = lane & 15;
  const int e0 = (lane >> 4) << 3;  // k-elem offset 0,8,16,24

  // A frag rows: mTile*128 + wm*64 + mi*16 + r16, k = kb*32 + e0 .. e0+7
  const float* aRow = X + (size_t)(mTile * BM + wm * 64 + r16) * K + e0;
  // B frag rows: nTile*128 + wn*64 + ni*16 + r16, col = h*32 + e0 .. e0+7
  // (mapping verified: identical to round-3's passing kernel)
  const float* wRow = W + (size_t)(nTile * BN + wn * 64 + r16) * redK + e0;

  auto loadA = [&](int kb, f32x4* r) {
    const float* p = aRow + (size_t)kb * BK;
#pragma unroll
    for (int mi = 0; mi < 4; ++mi) {
      const float* q = p + (size_t)(mi * 16) * K;
      r[2 * mi]     = *(const f32x4*)(q);
      r[2 * mi + 1] = *(const f32x4*)(q + 4);
    }
  };
  auto loadB = [&](int kb, f32x4* r) {
    const uint32_t kk = (uint32_t)kb * r0 + r2;
#pragma unroll
    for (int ni = 0; ni < 4; ++ni) {
      const uint32_t nb = (uint32_t)(nTile * (BN / 32) + wn * 2 + (ni >> 1));
      const uint32_t hv = (kk + nb * r1) ^ r3;
      const uint32_t h = pow2 ? (hv & redMask) : (hv % numRedKb);
      const float* q = wRow + (size_t)(ni * 16) * redK + h * 32u;
      r[2 * ni]     = *(const f32x4*)(q);
      r[2 * ni + 1] = *(const f32x4*)(q + 4);
    }
  };
  auto cvt = [&](const f32x4* s, bf16x8_t* d) {
#pragma unroll
    for (int i = 0; i < 4; ++i) {
      bf16x8_t t;
#pragma unroll
      for (int j = 0; j < 4; ++j) {
        t[j]     = (__bf16)s[2 * i][j];
        t[4 + j] = (__bf16)s[2 * i + 1][j];
      }
      d[i] = t;
    }
  };

  f32x4 acc[4][4] = {};
  auto mfma16 = [&](const bf16x8_t* af, const bf16x8_t* bb) {
#pragma unroll
    for (int mi = 0; mi < 4; ++mi)
#pragma unroll
      for (int ni = 0; ni < 4; ++ni)
        acc[mi][ni] = __builtin_amdgcn_mfma_f32_16x16x32_bf16(
            af[mi], bb[ni], acc[mi][ni], 0, 0, 0);
  };

  const int numKb = K / BK;
  const int kbN = numKb / KSPLIT;        // 64 (even)
  const int kb0 = kChunk * kbN;

  f32x4 aE[8], aO[8], bCur[8];           // A: 2-deep ping-pong; B: 1-deep
  loadA(kb0, aE);
  loadB(kb0, bCur);
  loadA(kb0 + 1, aO);

  bf16x8_t af[4], bb[4];
  for (int i = 0; i < kbN; i += 2) {
    // even step: consume aE, bCur(i)
    cvt(aE, af);
    cvt(bCur, bb);
    loadB(kb0 + i + 1, bCur);            // i+1 <= kbN-1 always here
    if (i + 2 < kbN) loadA(kb0 + i + 2, aE);
    mfma16(af, bb);

    // odd step: consume aO, bCur(i+1)
    cvt(aO, af);
    cvt(bCur, bb);
    if (i + 2 < kbN) loadB(kb0 + i + 2, bCur);
    if (i + 3 < kbN) loadA(kb0 + i + 3, aO);
    mfma16(af, bb);
  }

  // epilogue: C/D map col(n)=lane&15, row(m)=(lane>>4)*4+reg; atomic accumulate
  const int mBase = mTile * BM + (wm << 6);
  const int nBase = nTile * BN + (wn << 6);
#pragma unroll
  for (int ni = 0; ni < 4; ++ni) {
    const int n = nBase + (ni << 4) + (lane & 15);
#pragma unroll
    for (int mi = 0; mi < 4; ++mi) {
      const int m0 = mBase + (mi << 4) + ((lane >> 4) << 2);
#pragma unroll
      for (int r = 0; r < 4; ++r)
        unsafeAtomicAdd(&Out[(size_t)(m0 + r) * N + n], acc[mi][ni][r]);
    }
  }
}

extern "C" void kernel_launch(void* const* d_in, const int* in_sizes, int n_in,
                              void* d_out, int out_size, void* d_ws, size_t ws_size,
                              hipStream_t stream) {
  const float* X = (const float*)d_in[0];
  const float* W = (const float*)d_in[1];
  const float* Bias = (const float*)d_in[2];
  const int* RN = (const int*)d_in[3];
  float* Out = (float*)d_out;

  const int N = in_sizes[2];             // 512
  const int M = out_size / N;            // 8192
  const int K = in_sizes[0] / M;         // 8192
  const int redK = in_sizes[1] / N;      // 1024
  const uint32_t numRedKb = (uint32_t)(redK / 32);  // 32

  const int total4 = out_size / 4;
  init_out<<<(total4 + 255) / 256, 256, 0, stream>>>(Out, Bias, N, total4);

  const int mTiles = M / BM;             // 64
  const int nTiles = N / BN;             // 4
  dim3 grid(mTiles * nTiles * KSPLIT), block(256);
  ssl_gemm<<<grid, block, 0, stream>>>(X, W, RN, Out,
                                       M, N, K, redK, numRedKb, mTiles, nTiles);
}

// Round 5
// 619.198 us; speedup vs baseline: 1.2190x; 1.2190x over previous
//
#include <hip/hip_runtime.h>
#include <hip/hip_bf16.h>
#include <stdint.h>

// SSL hashed-sparse linear: out[M,N] = x[M,K] @ w_full[N,K]^T + bias
// w_full[n,k] = weight[n, h(n/32, k/32)*32 + k%32],
// h = ((kb*r0 + nb*r1 + r2) ^ r3) % num_red_kb   (uint32)
//
// fp32 in/out; compute in bf16 MFMA (threshold 0.165; absmax 0.03).
// HISTORY: r0/r2 (LDS 128x128 tile, 2-deep reg prefetch, 2 barriers/step,
//   split-K x4): 250us, MfmaUtil 11%, 2 blocks/CU (180 unified regs/wave).
//   r1 clamp->spills 567us. r3 1-deep B-direct 411us. r4 barrier-free
//   zero-LDS 502us. Conclusion: every pipe <15% busy at 2 blocks/CU;
//   deep prefetch + co-resident blocks carry r0; register footprint is the
//   binding constraint nobody successfully relaxed.
// ROUND-5 (this): m97-structure + SMALL ACC. BN 128->64 => acc[4][2] (32
//   VGPR, was 64). A staged fp32 via global_load_lds width=16 (zero staging
//   regs, 1 barrier/step). Swizzled-SOURCE LDS layout (rule 21: linear dest
//   + pre-swizzled global addr + XOR'd ds_read, slot^=(row&7)) kills the
//   128B-stride bank conflict. B: 2-deep reg prefetch (r0 pattern), hash now
//   wave-uniform (32 B-rows/wave = one n-block -> SALU). ~90-110 VGPR ->
//   launch_bounds(256,4) (cap 128; natural fits, no r1 crush). LDS 32KB ->
//   4 blocks/CU = 16 waves/CU. Grid 64m x 8n x 2k = 1024 = 1 generation;
//   id = mTile + 64*kChunk + 128*nTile so the 8 nTile blocks sharing an A
//   chunk land on one XCD (same id%8).
// Predicted: Occupancy ~45-50%, conflicts <2M, MfmaUtil 25-40%,
//   HBM 2-3.5 TB/s, ssl_gemm 250 -> 80-140us.

typedef __bf16 bf16x8_t __attribute__((ext_vector_type(8)));
typedef float f32x4 __attribute__((ext_vector_type(4)));

#define BM 128
#define BN 64
#define BK 32
#define KSPLIT 2

__global__ void init_out(float* __restrict__ Out, const float* __restrict__ Bias,
                         int N, int total4) {
  int i = blockIdx.x * blockDim.x + threadIdx.x;
  if (i < total4) {
    int idx = i << 2;
    int n = idx % N;                       // multiple of 4 since N%4==0
    *(f32x4*)(Out + idx) = *(const f32x4*)(Bias + n);
  }
}

__global__ __launch_bounds__(256, 4) void ssl_gemm(
    const float* __restrict__ X,       // [M,K]
    const float* __restrict__ W,       // [N,redK]
    const int* __restrict__ RN,        // [4]
    float* __restrict__ Out,           // [M,N], pre-seeded with bias
    int M, int N, int K, int redK, uint32_t numRedKb, int mTiles, int nTiles) {
  // A tile: 128 rows x 32 f32, double-buffered. Row = 8 slots of 16B.
  // LDS cell (row, slot) holds global (row, slot ^ (row&7)).
  __shared__ __align__(16) float As[2][BM * BK];

  const uint32_t r0 = (uint32_t)RN[0], r1 = (uint32_t)RN[1];
  const uint32_t r2 = (uint32_t)RN[2], r3 = (uint32_t)RN[3];
  const uint32_t redMask = numRedKb - 1u;
  const bool pow2 = (numRedKb & (numRedKb - 1u)) == 0u;

  const int id = blockIdx.x;
  const int mTile = id % mTiles;             // 0..63
  const int kChunk = (id / mTiles) % KSPLIT; // 0..1
  const int nTile = id / (mTiles * KSPLIT);  // 0..7

  const int tid = threadIdx.x;
  const int wave = tid >> 6;
  const int lane = tid & 63;
  const int wm = wave >> 1, wn = wave & 1;  // 2x2 wave grid: 64 rows x 32 cols

  const int r16 = lane & 15;
  const int x7 = lane & 7;
  const int e0 = (lane >> 4) << 3;  // f32 k-elem offset: 0,8,16,24

  // ---- A staging (global_load_lds, swizzled source) ----
  // Thread t covers (row = p*32 + t>>3, slot = t&7), 4 passes p.
  // LDS dest linear: buf base + p*4KB + tid*16 (wave-uniform base + lane*16).
  // Global source slot pre-swizzled: s' = (t&7) ^ ((t>>3)&7)  [row&7 inv. p]
  const int sRow = tid >> 3;                       // 0..31
  const int sSlot = (tid & 7) ^ (sRow & 7);
  const float* aSrc = X + (size_t)(mTile * BM + sRow) * K + sSlot * 4;

  auto stageA = [&](int buf, int kb) {
    const float* src = aSrc + (size_t)kb * BK;
#pragma unroll
    for (int p = 0; p < 4; ++p)
      __builtin_amdgcn_global_load_lds(
          (const __attribute__((address_space(1))) uint32_t*)(src + (size_t)p * 32 * K),
          (__attribute__((address_space(3))) uint32_t*)(&As[buf][p * 1024] + tid * 4),
          16, 0, 0);
  };

  // ---- B: direct to regs, 2-deep. Wave's 32 rows = ONE 32-row n-block ->
  // wave-uniform hash (SALU). Mapping identical to r3/r4 (passed).
  const int nRow0 = nTile * BN + wn * 32;          // wave's first B row
  const uint32_t nb = (uint32_t)(nRow0 >> 5);
  const float* wRow = W + (size_t)(nRow0 + r16) * redK + e0;

  auto loadB = [&](int kb, f32x4* r) {
    const uint32_t hv = ((uint32_t)kb * r0 + nb * r1 + r2) ^ r3;
    const uint32_t h = pow2 ? (hv & redMask) : (hv % numRedKb);
#pragma unroll
    for (int ni = 0; ni < 2; ++ni) {
      const float* q = wRow + (size_t)(ni * 16) * redK + h * 32u;
      r[2 * ni]     = *(const f32x4*)(q);
      r[2 * ni + 1] = *(const f32x4*)(q + 4);
    }
  };
  auto cvtB = [&](const f32x4* s, bf16x8_t* d) {
#pragma unroll
    for (int i = 0; i < 2; ++i) {
      bf16x8_t t;
#pragma unroll
      for (int j = 0; j < 4; ++j) {
        t[j]     = (__bf16)s[2 * i][j];
        t[4 + j] = (__bf16)s[2 * i + 1][j];
      }
      d[i] = t;
    }
  };

  // ---- A fragment read (swizzled ds_read) + cvt ----
  const int s0 = (lane >> 4) << 1;                 // 16B-slot: 0,2,4,6
  auto readA = [&](int buf, bf16x8_t* af) {
#pragma unroll
    for (int mi = 0; mi < 4; ++mi) {
      const int row = (wm << 6) + (mi << 4) + r16; // row&7 == lane&7
      const float* base = &As[buf][row * 32];
      f32x4 lo = *(const f32x4*)(base + ((s0 ^ x7) << 2));
      f32x4 hi = *(const f32x4*)(base + (((s0 + 1) ^ x7) << 2));
      bf16x8_t t;
#pragma unroll
      for (int j = 0; j < 4; ++j) {
        t[j]     = (__bf16)lo[j];
        t[4 + j] = (__bf16)hi[j];
      }
      af[mi] = t;
    }
  };

  f32x4 acc[4][2] = {};
  auto mfma8 = [&](const bf16x8_t* af, const bf16x8_t* bb) {
#pragma unroll
    for (int mi = 0; mi < 4; ++mi)
#pragma unroll
      for (int ni = 0; ni < 2; ++ni)
        acc[mi][ni] = __builtin_amdgcn_mfma_f32_16x16x32_bf16(
            af[mi], bb[ni], acc[mi][ni], 0, 0, 0);
  };

  const int numKb = K / BK;                 // 256
  const int kbN = numKb / KSPLIT;           // 128 (even)
  const int kb0 = kChunk * kbN;

  f32x4 b0[4], b1[4];
  bf16x8_t af[4], bb[2];

  stageA(0, kb0);
  loadB(kb0, b0);
  if (1 < kbN) loadB(kb0 + 1, b1);
  __syncthreads();                          // buf0 ready

  for (int i = 0; i < kbN; i += 2) {
    // even step: buf0, b0
    if (i + 1 < kbN) stageA(1, kb0 + i + 1);
    cvtB(b0, bb);
    if (i + 2 < kbN) loadB(kb0 + i + 2, b0);
    readA(0, af);
    mfma8(af, bb);
    __syncthreads();                        // buf1 staged + buf0 reads done

    // odd step: buf1, b1
    if (i + 1 < kbN) {
      if (i + 2 < kbN) stageA(0, kb0 + i + 2);
      cvtB(b1, bb);
      if (i + 3 < kbN) loadB(kb0 + i + 3, b1);
      readA(1, af);
      mfma8(af, bb);
      __syncthreads();
    }
  }

  // epilogue: C/D map col(n)=lane&15, row(m)=(lane>>4)*4+reg; atomic accumulate
  const int mBase = mTile * BM + (wm << 6);
  const int nBase = nTile * BN + (wn << 5);
#pragma unroll
  for (int ni = 0; ni < 2; ++ni) {
    const int n = nBase + (ni << 4) + (lane & 15);
#pragma unroll
    for (int mi = 0; mi < 4; ++mi) {
      const int m0 = mBase + (mi << 4) + ((lane >> 4) << 2);
#pragma unroll
      for (int r = 0; r < 4; ++r)
        unsafeAtomicAdd(&Out[(size_t)(m0 + r) * N + n], acc[mi][ni][r]);
    }
  }
}

extern "C" void kernel_launch(void* const* d_in, const int* in_sizes, int n_in,
                              void* d_out, int out_size, void* d_ws, size_t ws_size,
                              hipStream_t stream) {
  const float* X = (const float*)d_in[0];
  const float* W = (const float*)d_in[1];
  const float* Bias = (const float*)d_in[2];
  const int* RN = (const int*)d_in[3];
  float* Out = (float*)d_out;

  const int N = in_sizes[2];             // 512
  const int M = out_size / N;            // 8192
  const int K = in_sizes[0] / M;         // 8192
  const int redK = in_sizes[1] / N;      // 1024
  const uint32_t numRedKb = (uint32_t)(redK / 32);  // 32

  const int total4 = out_size / 4;
  init_out<<<(total4 + 255) / 256, 256, 0, stream>>>(Out, Bias, N, total4);

  const int mTiles = M / BM;             // 64
  const int nTiles = N / BN;             // 8
  dim3 grid(mTiles * KSPLIT * nTiles), block(256);  // 1024 = 1 generation
  ssl_gemm<<<grid, block, 0, stream>>>(X, W, RN, Out,
                                       M, N, K, redK, numRedKb, mTiles, nTiles);
}

// Round 6
// 612.185 us; speedup vs baseline: 1.2329x; 1.0115x over previous
//
#include <hip/hip_runtime.h>
#include <hip/hip_bf16.h>
#include <stdint.h>

// SSL hashed-sparse linear: out[M,N] = x[M,K] @ w_full[N,K]^T + bias
// w_full[n,k] = weight[n, h(n/32, k/32)*32 + k%32],
// h = ((kb*r0 + nb*r1 + r2) ^ r3) % num_red_kb   (uint32)
//
// fp32 in/out; bf16 MFMA (threshold 0.165; absmax 0.03).
// HISTORY: r0 248us (2-barrier drain, 2-deep reg prefetch). r2 counted-vmcnt
//   on reg-staged: neutral (compiler dep-waits re-serialize). r4 no-LDS 502us
//   (depth-2 regs << HBM latency). r5 global_load_lds ring-2 + syncthreads
//   drain: 367us, FETCH 563MB (L2 thrash: X-sharers 128 ids apart), conflicts
//   = only ~4cyc/ds_read (minor), no spills at acc[4][2].
//   Diagnosis: every K-step pays full loaded-HBM latency (~2-5K cyc) because
//   the drain kills the pipeline. This is exactly T3/T4 (m218: counted-vmcnt
//   vs drain0 = +38-73%).
// ROUND-6 (this): ring-3 LDS A-buffer + COUNTED vmcnt(8), never 0 in loop:
//   per step: vmcnt(8) [2 stages=32KB stay in flight] -> lgkm-only barrier ->
//   issue stage(i+2)+loadB(i+2) -> ds_read/cvt/8 MFMA. Main loop unrolled x6
//   (static buf%3/reg%2 indices, rule 20); 2 peeled tails drain 8->4->0.
//   Fixed id-map: 16 blocks sharing an mTile's X-chunk = 16 CONSECUTIVE slots
//   on one XCD (id = xcd + 8*slot) -> streaming L2 reuse (r5 had them 128
//   apart -> thrash). LDS 48KB -> 3 blocks/CU; (256,3) cap 170, natural
//   ~120-140, no r1-style crush.
// Predicted: 367 -> 100-150us, MfmaUtil 20-28%, HBM 2.5-3.5TB/s,
//   FETCH ~300MB, WRITE 32MB, Occupancy ~37%.

typedef __bf16 bf16x8_t __attribute__((ext_vector_type(8)));
typedef float f32x4 __attribute__((ext_vector_type(4)));

#define BM 128
#define BN 64
#define BK 32
#define KSPLIT 2
#define NBUF 3

__global__ void init_out(float* __restrict__ Out, const float* __restrict__ Bias,
                         int N, int total4) {
  int i = blockIdx.x * blockDim.x + threadIdx.x;
  if (i < total4) {
    int idx = i << 2;
    int n = idx % N;                       // multiple of 4 since N%4==0
    *(f32x4*)(Out + idx) = *(const f32x4*)(Bias + n);
  }
}

__global__ __launch_bounds__(256, 3) void ssl_gemm(
    const float* __restrict__ X,       // [M,K]
    const float* __restrict__ W,       // [N,redK]
    const int* __restrict__ RN,        // [4]
    float* __restrict__ Out,           // [M,N], pre-seeded with bias
    int M, int N, int K, int redK, uint32_t numRedKb, int mTiles, int nTiles) {
  // A ring: 3 bufs x 128 rows x 32 f32 (16KB each). Row = 8 slots of 16B.
  // LDS cell (row,slot) holds global (row, slot ^ (row&7)) [bank swizzle].
  __shared__ __align__(16) float As[NBUF][BM * BK];

  const uint32_t r0 = (uint32_t)RN[0], r1 = (uint32_t)RN[1];
  const uint32_t r2 = (uint32_t)RN[2], r3 = (uint32_t)RN[3];
  const uint32_t redMask = numRedKb - 1u;
  const bool pow2 = (numRedKb & (numRedKb - 1u)) == 0u;

  // id = xcd + 8*slot; each mTile's 16 blocks (8 nTile x 2 kChunk) are 16
  // CONSECUTIVE slots on ONE XCD -> they stream the same 2MB X-chunk through
  // that XCD's L2 together (temporal + spatial locality).
  const int id = blockIdx.x;
  const int xcd = id & 7;
  const int t = id >> 3;                  // 0..127: slot on this XCD
  const int mTile = ((t >> 4) << 3) + xcd;  // 0..63
  const int j = t & 15;
  const int nTile = j & 7;                // 0..7
  const int kChunk = j >> 3;              // 0..1

  const int tid = threadIdx.x;
  const int wave = tid >> 6;
  const int lane = tid & 63;
  const int wm = wave >> 1, wn = wave & 1;  // 2x2 waves: 64 rows x 32 cols

  const int r16 = lane & 15;
  const int x7 = lane & 7;
  const int e0 = (lane >> 4) << 3;        // f32 k-elem offset 0,8,16,24

  // ---- A staging (global_load_lds, pre-swizzled source) ----
  const int sRow = tid >> 3;              // 0..31
  const int sSlot = (tid & 7) ^ (sRow & 7);
  const float* aSrc = X + (size_t)(mTile * BM + sRow) * K + sSlot * 4;

  auto stageA = [&](int buf, int kb) {
    const float* src = aSrc + (size_t)kb * BK;
#pragma unroll
    for (int p = 0; p < 4; ++p)
      __builtin_amdgcn_global_load_lds(
          (const __attribute__((address_space(1))) uint32_t*)(src + (size_t)p * 32 * K),
          (__attribute__((address_space(3))) uint32_t*)(&As[buf][p * 1024] + tid * 4),
          16, 0, 0);
  };

  // ---- B: direct to regs (W is 2MB L2-resident), wave-uniform hash ----
  const int nRow0 = nTile * BN + wn * 32;
  const uint32_t nb = (uint32_t)(nRow0 >> 5);
  const float* wRow = W + (size_t)(nRow0 + r16) * redK + e0;

  auto loadB = [&](int kb, f32x4* r) {
    const uint32_t hv = ((uint32_t)kb * r0 + nb * r1 + r2) ^ r3;
    const uint32_t h = pow2 ? (hv & redMask) : (hv % numRedKb);
#pragma unroll
    for (int ni = 0; ni < 2; ++ni) {
      const float* q = wRow + (size_t)(ni * 16) * redK + h * 32u;
      r[2 * ni]     = *(const f32x4*)(q);
      r[2 * ni + 1] = *(const f32x4*)(q + 4);
    }
  };

  bf16x8_t af[4], bb[2];
  auto cvtB = [&](const f32x4* s) {
#pragma unroll
    for (int i = 0; i < 2; ++i) {
      bf16x8_t v;
#pragma unroll
      for (int jj = 0; jj < 4; ++jj) {
        v[jj]     = (__bf16)s[2 * i][jj];
        v[4 + jj] = (__bf16)s[2 * i + 1][jj];
      }
      bb[i] = v;
    }
  };

  const int s0 = (lane >> 4) << 1;        // 16B-slot 0,2,4,6
  auto readA = [&](int buf) {
#pragma unroll
    for (int mi = 0; mi < 4; ++mi) {
      const int row = (wm << 6) + (mi << 4) + r16;   // row&7 == x7
      const float* base = &As[buf][row * 32];
      f32x4 lo = *(const f32x4*)(base + ((s0 ^ x7) << 2));
      f32x4 hi = *(const f32x4*)(base + (((s0 + 1) ^ x7) << 2));
      bf16x8_t v;
#pragma unroll
      for (int jj = 0; jj < 4; ++jj) {
        v[jj]     = (__bf16)lo[jj];
        v[4 + jj] = (__bf16)hi[jj];
      }
      af[mi] = v;
    }
  };

  f32x4 acc[4][2] = {};
  auto mfma8 = [&]() {
#pragma unroll
    for (int mi = 0; mi < 4; ++mi)
#pragma unroll
      for (int ni = 0; ni < 2; ++ni)
        acc[mi][ni] = __builtin_amdgcn_mfma_f32_16x16x32_bf16(
            af[mi], bb[ni], acc[mi][ni], 0, 0, 0);
  };

  const int numKb = K / BK;               // 256
  const int kbN = numKb / KSPLIT;         // 128 (kbN-2 = 126 = 6*21)
  const int kb0 = kChunk * kbN;

  f32x4 bR0[4], bR1[4];
  // prologue: 2 stages + 2 B-loads in flight (16 VMEM instrs)
  stageA(0, kb0 + 0); loadB(kb0 + 0, bR0);
  stageA(1, kb0 + 1); loadB(kb0 + 1, bR1);

  // per step: vmcnt(8) leaves newest 2 {stage+loadB} groups in flight; the
  // oldest group (this step's buf + B regs) is guaranteed complete.
#define KSTEP_MAIN(BI, RI, KB)                                          \
  {                                                                     \
    __builtin_amdgcn_sched_barrier(0);                                  \
    asm volatile("s_waitcnt vmcnt(8)" ::: "memory");                    \
    asm volatile("s_waitcnt lgkmcnt(0)" ::: "memory");                  \
    __builtin_amdgcn_s_barrier();                                       \
    __builtin_amdgcn_sched_barrier(0);                                  \
    stageA((BI + 2) % NBUF, (KB) + 2);                                  \
    cvtB(bR##RI);                                                       \
    loadB((KB) + 2, bR##RI);                                            \
    __builtin_amdgcn_sched_barrier(0);                                  \
    readA(BI);                                                          \
    mfma8();                                                            \
  }

  for (int i = 0; i < kbN - 2; i += 6) {
    KSTEP_MAIN(0, 0, kb0 + i);
    KSTEP_MAIN(1, 1, kb0 + i + 1);
    KSTEP_MAIN(2, 0, kb0 + i + 2);
    KSTEP_MAIN(0, 1, kb0 + i + 3);
    KSTEP_MAIN(1, 0, kb0 + i + 4);
    KSTEP_MAIN(2, 1, kb0 + i + 5);
  }
#undef KSTEP_MAIN

  // tail i = kbN-2 (buf 0, reg 0): stage(kbN-2) is oldest of 16 in flight
  __builtin_amdgcn_sched_barrier(0);
  asm volatile("s_waitcnt vmcnt(8)" ::: "memory");
  asm volatile("s_waitcnt lgkmcnt(0)" ::: "memory");
  __builtin_amdgcn_s_barrier();
  __builtin_amdgcn_sched_barrier(0);
  cvtB(bR0);
  readA(0);
  mfma8();

  // tail i = kbN-1 (buf 1, reg 1): drain everything
  __builtin_amdgcn_sched_barrier(0);
  asm volatile("s_waitcnt vmcnt(0)" ::: "memory");
  asm volatile("s_waitcnt lgkmcnt(0)" ::: "memory");
  __builtin_amdgcn_s_barrier();
  __builtin_amdgcn_sched_barrier(0);
  cvtB(bR1);
  readA(1);
  mfma8();

  // epilogue: C/D map col(n)=lane&15, row(m)=(lane>>4)*4+reg; atomic accum
  const int mBase = mTile * BM + (wm << 6);
  const int nBase = nTile * BN + (wn << 5);
#pragma unroll
  for (int ni = 0; ni < 2; ++ni) {
    const int n = nBase + (ni << 4) + (lane & 15);
#pragma unroll
    for (int mi = 0; mi < 4; ++mi) {
      const int m0 = mBase + (mi << 4) + ((lane >> 4) << 2);
#pragma unroll
      for (int r = 0; r < 4; ++r)
        unsafeAtomicAdd(&Out[(size_t)(m0 + r) * N + n], acc[mi][ni][r]);
    }
  }
}

extern "C" void kernel_launch(void* const* d_in, const int* in_sizes, int n_in,
                              void* d_out, int out_size, void* d_ws, size_t ws_size,
                              hipStream_t stream) {
  const float* X = (const float*)d_in[0];
  const float* W = (const float*)d_in[1];
  const float* Bias = (const float*)d_in[2];
  const int* RN = (const int*)d_in[3];
  float* Out = (float*)d_out;

  const int N = in_sizes[2];             // 512
  const int M = out_size / N;            // 8192
  const int K = in_sizes[0] / M;         // 8192
  const int redK = in_sizes[1] / N;      // 1024
  const uint32_t numRedKb = (uint32_t)(redK / 32);  // 32

  const int total4 = out_size / 4;
  init_out<<<(total4 + 255) / 256, 256, 0, stream>>>(Out, Bias, N, total4);

  const int mTiles = M / BM;             // 64
  const int nTiles = N / BN;             // 8
  dim3 grid(mTiles * nTiles * KSPLIT), block(256);  // 1024
  ssl_gemm<<<grid, block, 0, stream>>>(X, W, RN, Out,
                                       M, N, K, redK, numRedKb, mTiles, nTiles);
}